// Round 8
// baseline (148.000 us; speedup 1.0000x reference)
//
#include <hip/hip_runtime.h>
#include <hip/hip_bf16.h>

#define B_ 4
#define S_ 4096
#define D_ 1024
#define H_ 64
#define SCALE_ 0.125f
#define WP_ 1056   // padded wq row stride (shorts)
#define SP_ 4224   // padded qT row stride (shorts)
#define NSPLIT 8

typedef __attribute__((ext_vector_type(8))) short bf16x8;
typedef __attribute__((ext_vector_type(4))) short bf16x4;
typedef __attribute__((ext_vector_type(4))) float f32x4;

// round-to-nearest-even f32 -> bf16 (finite inputs)
static __device__ __forceinline__ short f2bf(float f) {
    unsigned u = __builtin_bit_cast(unsigned, f);
    u += 0x7fffu + ((u >> 16) & 1u);
    return (short)(u >> 16);
}

// ---------------------------------------------------------------------------
// winit: wq f32 -> bf16 into padded [64][WP_] layout.
// ---------------------------------------------------------------------------
__global__ __launch_bounds__(256) void winit_kernel(
    const float* __restrict__ wq, short* __restrict__ wqb)
{
    const int i   = blockIdx.x * 256 + threadIdx.x;
    const int row = i >> 7;
    const int col = (i & 127) * 8;
    const float* s = wq + (size_t)row * D_ + col;
    bf16x8 v;
#pragma unroll
    for (int e = 0; e < 8; ++e) v[e] = f2bf(s[e]);
    *(bf16x8*)(wqb + (size_t)row * WP_ + col) = v;
}

// ---------------------------------------------------------------------------
// qproj: q = x @ wq^T (bf16 MFMA). Block = 16 output rows, 4 waves = 4
// K-quarters, coalesced 1KB wave-loads for x, LDS combine, writes q and
// channel-padded qT. (r7-proven)
// ---------------------------------------------------------------------------
__global__ __launch_bounds__(256) void qproj_mfma(
    const float* __restrict__ x, const short* __restrict__ wqb,
    short* __restrict__ q, short* __restrict__ qT)
{
    __shared__ short xs[4][16][264];
    __shared__ float cs[4][16][68];
    __shared__ short qs[16][68];

    const int tid  = threadIdx.x;
    const int wave = tid >> 6;
    const int lane = tid & 63;
    const int quad = lane >> 4;
    const int lr   = lane & 15;
    const int row0 = blockIdx.x * 16;

    {
        const float* xp = x + (size_t)row0 * D_ + wave * 256 + lane * 4;
#pragma unroll
        for (int s = 0; s < 16; ++s) {
            const f32x4 v = *(const f32x4*)(xp + (size_t)s * D_);
            unsigned long long pk = 0;
#pragma unroll
            for (int e = 0; e < 4; ++e)
                pk |= (unsigned long long)(unsigned short)f2bf(v[e]) << (16 * e);
            *(unsigned long long*)&xs[wave][s][lane * 4] = pk;
        }
    }
    __syncthreads();

    f32x4 acc[4];
#pragma unroll
    for (int nb = 0; nb < 4; ++nb) acc[nb] = (f32x4){0.f, 0.f, 0.f, 0.f};

    const short* wp = wqb + (size_t)lr * WP_ + wave * 256 + quad * 8;
#pragma unroll
    for (int t = 0; t < 8; ++t) {
        const bf16x8 a = *(const bf16x8*)&xs[wave][lr][t * 32 + quad * 8];
#pragma unroll
        for (int nb = 0; nb < 4; ++nb) {
            const bf16x8 bb = *(const bf16x8*)(wp + (size_t)(nb * 16) * WP_ + t * 32);
            acc[nb] = __builtin_amdgcn_mfma_f32_16x16x32_bf16(a, bb, acc[nb], 0, 0, 0);
        }
    }

#pragma unroll
    for (int nb = 0; nb < 4; ++nb)
#pragma unroll
        for (int i = 0; i < 4; ++i)
            cs[wave][quad * 4 + i][nb * 16 + lr] = acc[nb][i];
    __syncthreads();

    const int r  = tid >> 4;
    const int c4 = (tid & 15) * 4;
    unsigned long long pv = 0;
#pragma unroll
    for (int j = 0; j < 4; ++j) {
        const float s = cs[0][r][c4 + j] + cs[1][r][c4 + j]
                      + cs[2][r][c4 + j] + cs[3][r][c4 + j];
        pv |= (unsigned long long)(unsigned short)f2bf(s) << (16 * j);
    }
    *(unsigned long long*)(q + (size_t)(row0 + r) * H_ + c4) = pv;
    *(unsigned long long*)&qs[r][c4] = pv;
    __syncthreads();

    const int hh = tid >> 2;
    const int sj = (tid & 3) * 4;
    const int b  = row0 >> 12;
    const int sl = row0 & (S_ - 1);
    unsigned long long w = 0;
#pragma unroll
    for (int e = 0; e < 4; ++e)
        w |= (unsigned long long)(unsigned short)qs[sj + e][hh] << (16 * e);
    *(unsigned long long*)(qT + ((size_t)b * H_ + hh) * SP_ + sl + sj) = w;
}

// ---------------------------------------------------------------------------
// flash v5: transposed-score dataflow + 2 Q-sets per wave (32 q) so each
// shared kt/vt A-fragment read feeds 2 MFMAs. kt/vt are flat [64][64] with
// XOR-granule swizzle (conflict-free staging + reads, r6-proven). Per wave:
//   S^T = K Q^T (A = kt rows, B = resident qB[set]) for both sets,
//   P^T = exp -> plT[w][set] (packed b64), O += V^T x P^T sharing vt reads.
// Split-K over blockIdx.z; f32 partials to ws; no atomics.
// ---------------------------------------------------------------------------
__global__ __launch_bounds__(256, 4) void flash_mfma(
    const short* __restrict__ q, const short* __restrict__ qT,
    float* __restrict__ opart, float* __restrict__ lbuf)
{
    __shared__ short kt[64 * 64];        // [k-row][d], granule-swizzled
    __shared__ short vt[64 * 64];        // [h][k-col], granule-swizzled
    __shared__ short plT[4][2][16][72];  // per-wave,set P^T as [q][k]

    const int tid  = threadIdx.x;
    const int w    = tid >> 6;
    const int lane = tid & 63;
    const int quad = lane >> 4;
    const int lr   = lane & 15;
    const int b    = blockIdx.y;
    const int q0   = blockIdx.x * 128;
    const int z    = blockIdx.z;
    const int slice = S_ / gridDim.z;
    const int kbase = z * slice;
    const short* qb  = q  + (size_t)b * S_ * H_;
    const short* qTb = qT + (size_t)b * H_ * SP_;

    // resident Q B-frags, 2 sets of 16 q
    bf16x8 qB[2][2];
#pragma unroll
    for (int set = 0; set < 2; ++set) {
        const short* qr = qb + (size_t)(q0 + w * 32 + set * 16 + lr) * H_;
        qB[set][0] = *(const bf16x8*)(qr + quad * 8);
        qB[set][1] = *(const bf16x8*)(qr + 32 + quad * 8);
    }

    f32x4 o[2][4];
#pragma unroll
    for (int set = 0; set < 2; ++set)
#pragma unroll
        for (int mt = 0; mt < 4; ++mt) o[set][mt] = (f32x4){0.f, 0.f, 0.f, 0.f};
    float lacc[2] = {0.f, 0.f};

    // staging: thread -> row srow, granule pair g0,g0+1 (32B), XOR-swizzled
    const int srow = tid >> 2;            // 0..63
    const int g0   = (tid & 3) * 2;
    const int sw0  = (g0 ^ (srow & 7)) * 8;
    const int sw1  = ((g0 + 1) ^ (srow & 7)) * 8;
    const short* gk = qb  + (size_t)(kbase + srow) * H_ + g0 * 8;
    const short* gv = qTb + (size_t)srow * SP_ + kbase + g0 * 8;

    uint4 pk0 = *(const uint4*)gk, pk1 = *(const uint4*)(gk + 8);
    uint4 pv0 = *(const uint4*)gv, pv1 = *(const uint4*)(gv + 8);

    const int iters = slice >> 6;
    for (int it = 0; it < iters; ++it) {
        __syncthreads();                 // prev tiles consumed
        *(uint4*)&kt[srow * 64 + sw0] = pk0;
        *(uint4*)&kt[srow * 64 + sw1] = pk1;
        *(uint4*)&vt[srow * 64 + sw0] = pv0;
        *(uint4*)&vt[srow * 64 + sw1] = pv1;
        __syncthreads();                 // staging visible
        if (it + 1 < iters) {
            gk += (size_t)64 * H_;
            gv += 64;
            pk0 = *(const uint4*)gk; pk1 = *(const uint4*)(gk + 8);
            pv0 = *(const uint4*)gv; pv1 = *(const uint4*)(gv + 8);
        }

        // ---- S^T = K Q^T, both sets share each kt A-frag ----
        f32x4 s[2][4];
#pragma unroll
        for (int set = 0; set < 2; ++set)
#pragma unroll
            for (int mt = 0; mt < 4; ++mt) s[set][mt] = (f32x4){0.f, 0.f, 0.f, 0.f};
#pragma unroll
        for (int c = 0; c < 2; ++c)
#pragma unroll
            for (int mt = 0; mt < 4; ++mt) {
                const int row = mt * 16 + lr;
                const bf16x8 a = *(const bf16x8*)&kt[row * 64 + (((c * 4 + quad) ^ (row & 7)) * 8)];
                s[0][mt] = __builtin_amdgcn_mfma_f32_16x16x32_bf16(a, qB[0][c], s[0][mt], 0, 0, 0);
                s[1][mt] = __builtin_amdgcn_mfma_f32_16x16x32_bf16(a, qB[1][c], s[1][mt], 0, 0, 0);
            }

        // ---- P^T = exp(S^T*scale) -> plT; lane partial row sums ----
#pragma unroll
        for (int set = 0; set < 2; ++set)
#pragma unroll
            for (int mt = 0; mt < 4; ++mt) {
                bf16x4 pb;
#pragma unroll
                for (int i = 0; i < 4; ++i) {
                    const float p = __expf(s[set][mt][i] * SCALE_);
                    lacc[set] += p;
                    pb[i] = f2bf(p);
                }
                *(bf16x4*)&plT[w][set][lr][mt * 16 + quad * 4] = pb;
            }

        // ---- O += V^T x P^T, both sets share each vt A-frag ----
#pragma unroll
        for (int c = 0; c < 2; ++c) {
            const bf16x8 pB0 = *(const bf16x8*)&plT[w][0][lr][c * 32 + quad * 8];
            const bf16x8 pB1 = *(const bf16x8*)&plT[w][1][lr][c * 32 + quad * 8];
#pragma unroll
            for (int mt = 0; mt < 4; ++mt) {
                const int row = mt * 16 + lr;
                const bf16x8 a = *(const bf16x8*)&vt[row * 64 + (((c * 4 + quad) ^ (row & 7)) * 8)];
                o[0][mt] = __builtin_amdgcn_mfma_f32_16x16x32_bf16(a, pB0, o[0][mt], 0, 0, 0);
                o[1][mt] = __builtin_amdgcn_mfma_f32_16x16x32_bf16(a, pB1, o[1][mt], 0, 0, 0);
            }
        }
    }

    // ---- finish l across the 4 quads; write partials ----
#pragma unroll
    for (int set = 0; set < 2; ++set) {
        float v = lacc[set];
        v += __shfl_xor(v, 16, 64);
        v += __shfl_xor(v, 32, 64);
        float* ob = opart + (((size_t)z * B_ + b) * S_ + q0 + w * 32 + set * 16 + lr) * H_;
#pragma unroll
        for (int mt = 0; mt < 4; ++mt)
            *(f32x4*)(ob + mt * 16 + quad * 4) = o[set][mt];
        if (quad == 0)
            lbuf[((size_t)z * B_ + b) * S_ + q0 + w * 32 + set * 16 + lr] = v;
    }
}

// ---------------------------------------------------------------------------
// combine: out[row][:] = sum_z opart[z][row][:] / sum_z lbuf[z][row]
// ---------------------------------------------------------------------------
__global__ __launch_bounds__(256) void combine_kernel(
    const float* __restrict__ opart, const float* __restrict__ lbuf,
    float* __restrict__ out, int nsplit)
{
    const int t   = blockIdx.x * 256 + threadIdx.x;   // 262144
    const int row = t >> 4;
    const int c4  = (t & 15) * 4;
    f32x4 acc = (f32x4){0.f, 0.f, 0.f, 0.f};
    float l = 0.0f;
    for (int z = 0; z < nsplit; ++z) {
        const f32x4 v = *(const f32x4*)(opart + ((size_t)z * (B_ * S_) + row) * H_ + c4);
        acc[0] += v[0]; acc[1] += v[1]; acc[2] += v[2]; acc[3] += v[3];
        l += lbuf[(size_t)z * (B_ * S_) + row];
    }
    const float r = 1.0f / l;
    acc[0] *= r; acc[1] *= r; acc[2] *= r; acc[3] *= r;
    *(f32x4*)(out + (size_t)row * H_ + c4) = acc;
}

extern "C" void kernel_launch(void* const* d_in, const int* in_sizes, int n_in,
                              void* d_out, int out_size, void* d_ws, size_t ws_size,
                              hipStream_t stream) {
    const float* x  = (const float*)d_in[0];   // [4,4096,1024] f32
    const float* wq = (const float*)d_in[1];   // [64,1024] f32
    float* out = (float*)d_out;                // [4,4096,64] f32

    const size_t off_qT  = 2097152;                               // q: 2 MiB
    const size_t off_wqb = off_qT + (size_t)B_ * H_ * SP_ * 2;    // qT padded
    const size_t off_op  = off_wqb + (size_t)H_ * WP_ * 2;        // wqb padded
    short* qbuf = (short*)d_ws;
    short* qT   = (short*)((char*)d_ws + off_qT);
    short* wqb  = (short*)((char*)d_ws + off_wqb);

    const size_t per_split = (size_t)B_ * S_ * H_ * 4 + (size_t)B_ * S_ * 4;
    int nsplit = NSPLIT;
    while (nsplit > 1 && ws_size < off_op + (size_t)nsplit * per_split) nsplit >>= 1;
    float* opart = (float*)((char*)d_ws + off_op);
    float* lbuf  = (float*)((char*)d_ws + off_op + (size_t)nsplit * B_ * S_ * H_ * 4);

    winit_kernel<<<dim3(32), dim3(256), 0, stream>>>(wq, wqb);
    qproj_mfma<<<dim3((B_ * S_) / 16), dim3(256), 0, stream>>>(x, wqb, qbuf, qT);
    flash_mfma<<<dim3(S_ / 128, B_, nsplit), dim3(256), 0, stream>>>(qbuf, qT, opart, lbuf);
    combine_kernel<<<dim3(1024), dim3(256), 0, stream>>>(opart, lbuf, out, nsplit);
}

// Round 9
// 134.312 us; speedup vs baseline: 1.1019x; 1.1019x over previous
//
#include <hip/hip_runtime.h>
#include <hip/hip_bf16.h>

#define B_ 4
#define S_ 4096
#define D_ 1024
#define H_ 64
#define SCALE_ 0.125f
#define CFAC_ 0.180336884f   // SCALE * log2(e): exp(s*SCALE) == exp2(s*CFAC_)
#define WP_ 1056   // padded wq row stride (shorts)
#define SP_ 4224   // padded qT row stride (shorts)
#define NSPLIT 4

typedef __attribute__((ext_vector_type(8))) short bf16x8;
typedef __attribute__((ext_vector_type(4))) float f32x4;

// round-to-nearest-even f32 -> bf16 (finite inputs)
static __device__ __forceinline__ short f2bf(float f) {
    unsigned u = __builtin_bit_cast(unsigned, f);
    u += 0x7fffu + ((u >> 16) & 1u);
    return (short)(u >> 16);
}

// truncating pack: two f32 -> bf16x2 in one u32 (hi = f1, lo = f0)
static __device__ __forceinline__ unsigned pk_trunc(float f0, float f1) {
    return (__builtin_bit_cast(unsigned, f1) & 0xffff0000u)
         | (__builtin_bit_cast(unsigned, f0) >> 16);
}

// ---------------------------------------------------------------------------
// winit: wq f32 -> bf16 into padded [64][WP_] layout.
// ---------------------------------------------------------------------------
__global__ __launch_bounds__(256) void winit_kernel(
    const float* __restrict__ wq, short* __restrict__ wqb)
{
    const int i   = blockIdx.x * 256 + threadIdx.x;
    const int row = i >> 7;
    const int col = (i & 127) * 8;
    const float* s = wq + (size_t)row * D_ + col;
    bf16x8 v;
#pragma unroll
    for (int e = 0; e < 8; ++e) v[e] = f2bf(s[e]);
    *(bf16x8*)(wqb + (size_t)row * WP_ + col) = v;
}

// ---------------------------------------------------------------------------
// qproj: q = x @ wq^T (bf16 MFMA). Writes q (unscaled), qT (padded transpose)
// and qs_scaled = f2bf(q * CFAC_) for the flash exp2 fast path.
// ---------------------------------------------------------------------------
__global__ __launch_bounds__(256) void qproj_mfma(
    const float* __restrict__ x, const short* __restrict__ wqb,
    short* __restrict__ q, short* __restrict__ qT, short* __restrict__ qsb)
{
    __shared__ short xs[4][16][264];
    __shared__ float cs[4][16][68];
    __shared__ short qs[16][68];

    const int tid  = threadIdx.x;
    const int wave = tid >> 6;
    const int lane = tid & 63;
    const int quad = lane >> 4;
    const int lr   = lane & 15;
    const int row0 = blockIdx.x * 16;

    {
        const float* xp = x + (size_t)row0 * D_ + wave * 256 + lane * 4;
#pragma unroll
        for (int s = 0; s < 16; ++s) {
            const f32x4 v = *(const f32x4*)(xp + (size_t)s * D_);
            unsigned long long pk = 0;
#pragma unroll
            for (int e = 0; e < 4; ++e)
                pk |= (unsigned long long)(unsigned short)f2bf(v[e]) << (16 * e);
            *(unsigned long long*)&xs[wave][s][lane * 4] = pk;
        }
    }
    __syncthreads();

    f32x4 acc[4];
#pragma unroll
    for (int nb = 0; nb < 4; ++nb) acc[nb] = (f32x4){0.f, 0.f, 0.f, 0.f};

    const short* wp = wqb + (size_t)lr * WP_ + wave * 256 + quad * 8;
#pragma unroll
    for (int t = 0; t < 8; ++t) {
        const bf16x8 a = *(const bf16x8*)&xs[wave][lr][t * 32 + quad * 8];
#pragma unroll
        for (int nb = 0; nb < 4; ++nb) {
            const bf16x8 bb = *(const bf16x8*)(wp + (size_t)(nb * 16) * WP_ + t * 32);
            acc[nb] = __builtin_amdgcn_mfma_f32_16x16x32_bf16(a, bb, acc[nb], 0, 0, 0);
        }
    }

#pragma unroll
    for (int nb = 0; nb < 4; ++nb)
#pragma unroll
        for (int i = 0; i < 4; ++i)
            cs[wave][quad * 4 + i][nb * 16 + lr] = acc[nb][i];
    __syncthreads();

    const int r  = tid >> 4;
    const int c4 = (tid & 15) * 4;
    unsigned long long pv = 0, pw = 0;
#pragma unroll
    for (int j = 0; j < 4; ++j) {
        const float s = cs[0][r][c4 + j] + cs[1][r][c4 + j]
                      + cs[2][r][c4 + j] + cs[3][r][c4 + j];
        pv |= (unsigned long long)(unsigned short)f2bf(s) << (16 * j);
        pw |= (unsigned long long)(unsigned short)f2bf(s * CFAC_) << (16 * j);
    }
    *(unsigned long long*)(q   + (size_t)(row0 + r) * H_ + c4) = pv;
    *(unsigned long long*)(qsb + (size_t)(row0 + r) * H_ + c4) = pw;
    *(unsigned long long*)&qs[r][c4] = pv;
    __syncthreads();

    const int hh = tid >> 2;
    const int sj = (tid & 3) * 4;
    const int b  = row0 >> 12;
    const int sl = row0 & (S_ - 1);
    unsigned long long w = 0;
#pragma unroll
    for (int e = 0; e < 4; ++e)
        w |= (unsigned long long)(unsigned short)qs[sj + e][hh] << (16 * e);
    *(unsigned long long*)(qT + ((size_t)b * H_ + hh) * SP_ + sl + sj) = w;
}

// ---------------------------------------------------------------------------
// flash v6: transposed-score dataflow (r7) + XOR-granule swizzle (r8) +
// VALU diet: exp2 with pre-scaled Q, truncating P pack, row-sums via an
// extra MFMA against a ones A-fragment (no shuffles, no VALU adds).
// 1 Q-set per wave (spill-free: ~60 arch VGPR + ~20 acc << 128 cap).
// ---------------------------------------------------------------------------
__global__ __launch_bounds__(256, 4) void flash_mfma(
    const short* __restrict__ q, const short* __restrict__ qT,
    const short* __restrict__ qsb,
    float* __restrict__ opart, float* __restrict__ lbuf)
{
    __shared__ short kt[64 * 64];      // [k-row][d], granule-swizzled
    __shared__ short vt[64 * 64];      // [h][k-col], granule-swizzled
    __shared__ short plT[4][16][72];   // per-wave P^T as [q][k]

    const int tid  = threadIdx.x;
    const int w    = tid >> 6;
    const int lane = tid & 63;
    const int quad = lane >> 4;
    const int lr   = lane & 15;
    const int b    = blockIdx.y;
    const int q0   = blockIdx.x * 64;
    const int z    = blockIdx.z;
    const int slice = S_ / gridDim.z;
    const int kbase = z * slice;
    const short* qb  = q  + (size_t)b * S_ * H_;
    const short* qTb = qT + (size_t)b * H_ * SP_;

    // resident scaled-Q B-frags: B[k=d=quad*8+j][n=q=lr]
    bf16x8 qB[2];
    {
        const short* qr = qsb + (size_t)(b * S_ + q0 + w * 16 + lr) * H_;
        qB[0] = *(const bf16x8*)(qr + quad * 8);
        qB[1] = *(const bf16x8*)(qr + 32 + quad * 8);
    }

    // ones A-fragment for the l-sum MFMA (bf16 1.0 = 0x3f80)
    bf16x8 ones;
#pragma unroll
    for (int e = 0; e < 8; ++e) ones[e] = (short)0x3f80;

    f32x4 o[4];
#pragma unroll
    for (int mt = 0; mt < 4; ++mt) o[mt] = (f32x4){0.f, 0.f, 0.f, 0.f};
    f32x4 lsum = (f32x4){0.f, 0.f, 0.f, 0.f};

    // staging: thread -> row srow, granule pair (32B), XOR-swizzled dest
    const int srow = tid >> 2;            // 0..63
    const int g0   = (tid & 3) * 2;
    const int sw0  = (g0 ^ (srow & 7)) * 8;
    const int sw1  = ((g0 + 1) ^ (srow & 7)) * 8;
    const short* gk = qb  + (size_t)(kbase + srow) * H_ + g0 * 8;
    const short* gv = qTb + (size_t)srow * SP_ + kbase + g0 * 8;

    uint4 pk0 = *(const uint4*)gk, pk1 = *(const uint4*)(gk + 8);
    uint4 pv0 = *(const uint4*)gv, pv1 = *(const uint4*)(gv + 8);

    const int iters = slice >> 6;
    for (int it = 0; it < iters; ++it) {
        __syncthreads();               // prev tiles consumed
        *(uint4*)&kt[srow * 64 + sw0] = pk0;
        *(uint4*)&kt[srow * 64 + sw1] = pk1;
        *(uint4*)&vt[srow * 64 + sw0] = pv0;
        *(uint4*)&vt[srow * 64 + sw1] = pv1;
        __syncthreads();               // staging visible
        if (it + 1 < iters) {
            gk += (size_t)64 * H_;
            gv += 64;
            pk0 = *(const uint4*)gk; pk1 = *(const uint4*)(gk + 8);
            pv0 = *(const uint4*)gv; pv1 = *(const uint4*)(gv + 8);
        }

        // ---- S^T = K (cQ)^T ----
        f32x4 s[4];
#pragma unroll
        for (int mt = 0; mt < 4; ++mt) s[mt] = (f32x4){0.f, 0.f, 0.f, 0.f};
#pragma unroll
        for (int c = 0; c < 2; ++c)
#pragma unroll
            for (int mt = 0; mt < 4; ++mt) {
                const int row = mt * 16 + lr;
                const bf16x8 a = *(const bf16x8*)&kt[row * 64 + (((c * 4 + quad) ^ (row & 7)) * 8)];
                s[mt] = __builtin_amdgcn_mfma_f32_16x16x32_bf16(a, qB[c], s[mt], 0, 0, 0);
            }

        // ---- P^T = exp2(S^T); truncating pack -> plT ----
#pragma unroll
        for (int mt = 0; mt < 4; ++mt) {
            const float p0 = __builtin_amdgcn_exp2f(s[mt][0]);
            const float p1 = __builtin_amdgcn_exp2f(s[mt][1]);
            const float p2 = __builtin_amdgcn_exp2f(s[mt][2]);
            const float p3 = __builtin_amdgcn_exp2f(s[mt][3]);
            unsigned lohi[2];
            lohi[0] = pk_trunc(p0, p1);
            lohi[1] = pk_trunc(p2, p3);
            *(unsigned long long*)&plT[w][lr][mt * 16 + quad * 4] =
                *(unsigned long long*)lohi;
        }

        // ---- O += V^T x P^T ; l += ones x P^T (matrix-pipe row sums) ----
#pragma unroll
        for (int c = 0; c < 2; ++c) {
            const bf16x8 pB = *(const bf16x8*)&plT[w][lr][c * 32 + quad * 8];
            lsum = __builtin_amdgcn_mfma_f32_16x16x32_bf16(ones, pB, lsum, 0, 0, 0);
#pragma unroll
            for (int mt = 0; mt < 4; ++mt) {
                const int row = mt * 16 + lr;
                const bf16x8 a = *(const bf16x8*)&vt[row * 64 + (((c * 4 + quad) ^ (row & 7)) * 8)];
                o[mt] = __builtin_amdgcn_mfma_f32_16x16x32_bf16(a, pB, o[mt], 0, 0, 0);
            }
        }
    }

    // ---- write partials: O[q=lr][h=mt*16+quad*4+i]; l = lsum[0] (full) ----
    float* ob = opart + (((size_t)z * B_ + b) * S_ + q0 + w * 16 + lr) * H_;
#pragma unroll
    for (int mt = 0; mt < 4; ++mt)
        *(f32x4*)(ob + mt * 16 + quad * 4) = o[mt];
    if (quad == 0)
        lbuf[((size_t)z * B_ + b) * S_ + q0 + w * 16 + lr] = lsum[0];
}

// ---------------------------------------------------------------------------
// combine: out[row][:] = sum_z opart[z][row][:] / sum_z lbuf[z][row]
// ---------------------------------------------------------------------------
__global__ __launch_bounds__(256) void combine_kernel(
    const float* __restrict__ opart, const float* __restrict__ lbuf,
    float* __restrict__ out, int nsplit)
{
    const int t   = blockIdx.x * 256 + threadIdx.x;   // 262144
    const int row = t >> 4;
    const int c4  = (t & 15) * 4;
    f32x4 acc = (f32x4){0.f, 0.f, 0.f, 0.f};
    float l = 0.0f;
    for (int z = 0; z < nsplit; ++z) {
        const f32x4 v = *(const f32x4*)(opart + ((size_t)z * (B_ * S_) + row) * H_ + c4);
        acc[0] += v[0]; acc[1] += v[1]; acc[2] += v[2]; acc[3] += v[3];
        l += lbuf[(size_t)z * (B_ * S_) + row];
    }
    const float r = 1.0f / l;
    acc[0] *= r; acc[1] *= r; acc[2] *= r; acc[3] *= r;
    *(f32x4*)(out + (size_t)row * H_ + c4) = acc;
}

extern "C" void kernel_launch(void* const* d_in, const int* in_sizes, int n_in,
                              void* d_out, int out_size, void* d_ws, size_t ws_size,
                              hipStream_t stream) {
    const float* x  = (const float*)d_in[0];   // [4,4096,1024] f32
    const float* wq = (const float*)d_in[1];   // [64,1024] f32
    float* out = (float*)d_out;                // [4,4096,64] f32

    const size_t off_qT  = 2097152;                               // q: 2 MiB
    const size_t off_wqb = off_qT + (size_t)B_ * H_ * SP_ * 2;    // qT padded
    const size_t off_qsb = off_wqb + (size_t)H_ * WP_ * 2;        // wqb padded
    const size_t off_op  = off_qsb + 2097152;                     // qsb 2 MiB
    short* qbuf = (short*)d_ws;
    short* qT   = (short*)((char*)d_ws + off_qT);
    short* wqb  = (short*)((char*)d_ws + off_wqb);
    short* qsb  = (short*)((char*)d_ws + off_qsb);

    const size_t per_split = (size_t)B_ * S_ * H_ * 4 + (size_t)B_ * S_ * 4;
    int nsplit = NSPLIT;
    while (nsplit > 1 && ws_size < off_op + (size_t)nsplit * per_split) nsplit >>= 1;
    float* opart = (float*)((char*)d_ws + off_op);
    float* lbuf  = (float*)((char*)d_ws + off_op + (size_t)nsplit * B_ * S_ * H_ * 4);

    winit_kernel<<<dim3(32), dim3(256), 0, stream>>>(wq, wqb);
    qproj_mfma<<<dim3((B_ * S_) / 16), dim3(256), 0, stream>>>(x, wqb, qbuf, qT, qsb);
    flash_mfma<<<dim3(S_ / 64, B_, nsplit), dim3(256), 0, stream>>>(qbuf, qT, qsb, opart, lbuf);
    combine_kernel<<<dim3(1024), dim3(256), 0, stream>>>(opart, lbuf, out, nsplit);
}